// Round 1
// baseline (775.011 us; speedup 1.0000x reference)
//
#include <hip/hip_runtime.h>
#include <hip/hip_bf16.h>

#define HH 128
#define LL 4
#define BB 128
#define NPGC 32
#define NNODE (BB*NPGC)      // 4096
#define NEDGE (NNODE*NPGC)   // 131072
#define NFREQ 10
#define DISD 60
#define EIN 325              // 2*HH + 9 + DISD

__device__ __forceinline__ float silu_f(float x) {
    return x / (1.0f + __expf(-x));
}

// lat_ip[b][i*3+k] = sum_j lat[b,i,j]*lat[b,k,j]
__global__ void k_lat(const float* __restrict__ lat, float* __restrict__ lat_ip) {
    int b = blockIdx.x;
    int t = threadIdx.x;
    if (t < 9) {
        int i = t / 3, k = t % 3;
        const float* lb = lat + b * 9;
        float s = lb[i*3+0]*lb[k*3+0] + lb[i*3+1]*lb[k*3+1] + lb[i*3+2]*lb[k*3+2];
        lat_ip[b*9 + t] = s;
    }
}

// Cc[l][b][c] = edge_b1[l][c] + sum_{k<9} lat_ip[b][k] * ew1[l][256+k][c]
__global__ void k_cc(const float* __restrict__ lat_ip, const float* __restrict__ ew1,
                     const float* __restrict__ eb1, float* __restrict__ Cc) {
    int blk = blockIdx.x;        // l*BB + b
    int l = blk / BB, b = blk % BB;
    int c = threadIdx.x;
    float acc = eb1[l*HH + c];
    #pragma unroll
    for (int k = 0; k < 9; ++k)
        acc += lat_ip[b*9+k] * ew1[((size_t)l*EIN + 2*HH + k)*HH + c];
    Cc[(size_t)blk*HH + c] = acc;
}

// h0 gather
__global__ void k_h0(const int* __restrict__ at, const float* __restrict__ emb,
                     float* __restrict__ h) {
    int idx = blockIdx.x * blockDim.x + threadIdx.x;   // < NNODE*HH
    int n = idx >> 7, c = idx & 127;
    h[idx] = emb[(at[n]-1)*HH + c];
}

// dis stored transposed: disT[col][e], col 0..59
__global__ void k_dis(const float* __restrict__ frac, float* __restrict__ disT) {
    int e = blockIdx.x * blockDim.x + threadIdx.x;  // < NEDGE
    int b = e >> 10, r = e & 1023, i = r >> 5, j = r & 31;
    int src = b*32 + i, dst = b*32 + j;
    float dx[3];
    #pragma unroll
    for (int d = 0; d < 3; ++d) dx[d] = frac[dst*3+d] - frac[src*3+d];
    #pragma unroll
    for (int d = 0; d < 3; ++d) {
        #pragma unroll
        for (int k = 0; k < NFREQ; ++k) {
            float ang = 6.28318530717958647692f * (float)k * dx[d];
            disT[(size_t)(d*NFREQ + k)*NEDGE + e] = sinf(ang);
            disT[(size_t)(30 + d*NFREQ + k)*NEDGE + e] = cosf(ang);
        }
    }
}

// A[n][c] = sum_k h[n][k]*ew1l[k][c];  Bv[n][c] = sum_k h[n][k]*ew1l[128+k][c]
__global__ __launch_bounds__(256) void k_ab(const float* __restrict__ h,
                     const float* __restrict__ ew1l,
                     float* __restrict__ A, float* __restrict__ Bv) {
    __shared__ float sm_h[16][HH];
    int n0 = blockIdx.x * 16;
    int t = threadIdx.x;
    for (int idx = t; idx < 16*HH; idx += 256)
        sm_h[idx >> 7][idx & 127] = h[(size_t)n0*HH + idx];
    __syncthreads();
    int half = t >> 7, c = t & 127;
    const float* w = ew1l + (size_t)half*HH*HH;
    float acc[16];
    #pragma unroll
    for (int q = 0; q < 16; ++q) acc[q] = 0.f;
    for (int k = 0; k < HH; ++k) {
        float wv = w[k*HH + c];
        #pragma unroll
        for (int q = 0; q < 16; ++q) acc[q] += sm_h[q][k] * wv;
    }
    float* outp = half ? Bv : A;
    #pragma unroll
    for (int q = 0; q < 16; ++q) outp[(size_t)(n0+q)*HH + c] = acc[q];
}

// per-node edge pipeline: m1 = A[i]+Bv[dst]+Cc[b]+dis@W1d -> silu -> @W2+b2 -> silu -> mean_j
__global__ __launch_bounds__(256) void k_edge(
    const float* __restrict__ A, const float* __restrict__ Bv,
    const float* __restrict__ Cc_l, const float* __restrict__ disT,
    const float* __restrict__ w1d,   // ew1 + (l*EIN+265)*HH
    const float* __restrict__ w2,    // ew2 + l*HH*HH
    const float* __restrict__ b2,    // eb2 + l*HH
    float* __restrict__ agg) {
    __shared__ float sm_dis[NPGC][DISD];
    __shared__ float sm_s[NPGC][HH];
    __shared__ float sm_red[2][HH];
    int i = blockIdx.x;           // src node
    int b = i >> 5;
    int ebase = b*1024 + (i & 31)*32;
    int t = threadIdx.x;
    for (int idx = t; idx < NPGC*DISD; idx += 256) {
        int k = idx >> 5, j = idx & 31;
        sm_dis[j][k] = disT[(size_t)k*NEDGE + ebase + j];
    }
    __syncthreads();
    int c = t & 127, jh = t >> 7;
    float base = A[(size_t)i*HH + c] + Cc_l[(size_t)b*HH + c];
    float acc[16];
    #pragma unroll
    for (int jj = 0; jj < 16; ++jj)
        acc[jj] = base + Bv[(size_t)(b*32 + jh*16 + jj)*HH + c];
    for (int k = 0; k < DISD; ++k) {
        float wv = w1d[k*HH + c];
        #pragma unroll
        for (int jj = 0; jj < 16; ++jj)
            acc[jj] += sm_dis[jh*16+jj][k] * wv;
    }
    #pragma unroll
    for (int jj = 0; jj < 16; ++jj)
        sm_s[jh*16+jj][c] = silu_f(acc[jj]);
    __syncthreads();
    float bias = b2[c];
    float acc2[16];
    #pragma unroll
    for (int jj = 0; jj < 16; ++jj) acc2[jj] = bias;
    for (int k = 0; k < HH; ++k) {
        float wv = w2[k*HH + c];
        #pragma unroll
        for (int jj = 0; jj < 16; ++jj)
            acc2[jj] += sm_s[jh*16+jj][k] * wv;
    }
    float red = 0.f;
    #pragma unroll
    for (int jj = 0; jj < 16; ++jj) red += silu_f(acc2[jj]);
    sm_red[jh][c] = red;
    __syncthreads();
    if (t < HH)
        agg[(size_t)i*HH + t] = (sm_red[0][t] + sm_red[1][t]) * (1.0f/NPGC);
}

// node MLP + residual
__global__ __launch_bounds__(128) void k_node(float* __restrict__ h, const float* __restrict__ agg,
                       const float* __restrict__ nw1, const float* __restrict__ nb1,
                       const float* __restrict__ nw2, const float* __restrict__ nb2) {
    __shared__ float sm_in[2*HH];
    __shared__ float sm_u1[HH];
    int n = blockIdx.x, c = threadIdx.x;
    sm_in[c] = h[(size_t)n*HH + c];
    sm_in[HH + c] = agg[(size_t)n*HH + c];
    __syncthreads();
    float acc = nb1[c];
    for (int k = 0; k < 2*HH; ++k) acc += sm_in[k] * nw1[k*HH + c];
    sm_u1[c] = silu_f(acc);
    __syncthreads();
    float acc2 = nb2[c];
    for (int k = 0; k < HH; ++k) acc2 += sm_u1[k] * nw2[k*HH + c];
    h[(size_t)n*HH + c] += silu_f(acc2);
}

// graph mean-pool + out projection
__global__ __launch_bounds__(128) void k_pool(const float* __restrict__ h, const float* __restrict__ ow,
                       float* __restrict__ out) {
    __shared__ float sm_g[HH];
    int b = blockIdx.x, c = threadIdx.x;
    float s = 0.f;
    for (int n = 0; n < NPGC; ++n) s += h[(size_t)(b*NPGC+n)*HH + c];
    sm_g[c] = s * (1.0f/NPGC);
    __syncthreads();
    float acc = 0.f;
    for (int k = 0; k < HH; ++k) acc += sm_g[k] * ow[k*HH + c];
    out[(size_t)b*HH + c] = acc;
}

extern "C" void kernel_launch(void* const* d_in, const int* in_sizes, int n_in,
                              void* d_out, int out_size, void* d_ws, size_t ws_size,
                              hipStream_t stream) {
    const int*   atom_types = (const int*)d_in[0];
    const float* frac       = (const float*)d_in[1];
    const float* lat        = (const float*)d_in[2];
    // d_in[3] = edges, d_in[4] = node2graph: dense per-graph structure is known
    const float* node_emb   = (const float*)d_in[5];
    const float* ew1        = (const float*)d_in[6];
    const float* eb1        = (const float*)d_in[7];
    const float* ew2        = (const float*)d_in[8];
    const float* eb2        = (const float*)d_in[9];
    const float* nw1        = (const float*)d_in[10];
    const float* nb1        = (const float*)d_in[11];
    const float* nw2        = (const float*)d_in[12];
    const float* nb2        = (const float*)d_in[13];
    const float* ow         = (const float*)d_in[14];
    float* out = (float*)d_out;

    char* ws = (char*)d_ws;
    float* disT   = (float*)ws;  ws += (size_t)DISD*NEDGE*4;   // 31.5 MB
    float* h      = (float*)ws;  ws += (size_t)NNODE*HH*4;     // 2 MB
    float* A      = (float*)ws;  ws += (size_t)NNODE*HH*4;
    float* Bv     = (float*)ws;  ws += (size_t)NNODE*HH*4;
    float* agg    = (float*)ws;  ws += (size_t)NNODE*HH*4;
    float* lat_ip = (float*)ws;  ws += 8192;                   // BB*9*4 padded
    float* Cc     = (float*)ws;  ws += (size_t)LL*BB*HH*4;

    k_lat<<<BB, 64, 0, stream>>>(lat, lat_ip);
    k_cc<<<LL*BB, HH, 0, stream>>>(lat_ip, ew1, eb1, Cc);
    k_h0<<<(NNODE*HH)/256, 256, 0, stream>>>(atom_types, node_emb, h);
    k_dis<<<NEDGE/256, 256, 0, stream>>>(frac, disT);

    for (int l = 0; l < LL; ++l) {
        k_ab<<<NNODE/16, 256, 0, stream>>>(h, ew1 + (size_t)l*EIN*HH, A, Bv);
        k_edge<<<NNODE, 256, 0, stream>>>(A, Bv, Cc + (size_t)l*BB*HH, disT,
                                          ew1 + ((size_t)l*EIN + 2*HH + 9)*HH,
                                          ew2 + (size_t)l*HH*HH, eb2 + (size_t)l*HH, agg);
        k_node<<<NNODE, HH, 0, stream>>>(h, agg,
                                         nw1 + (size_t)l*2*HH*HH, nb1 + (size_t)l*HH,
                                         nw2 + (size_t)l*HH*HH, nb2 + (size_t)l*HH);
    }
    k_pool<<<BB, HH, 0, stream>>>(h, ow, out);
}

// Round 2
// 385.718 us; speedup vs baseline: 2.0093x; 2.0093x over previous
//
#include <hip/hip_runtime.h>
#include <hip/hip_bf16.h>
#include <cstdint>

#define HH 128
#define LL 4
#define BB 128
#define NPGC 32
#define NNODE (BB*NPGC)      // 4096
#define NEDGE (NNODE*NPGC)   // 131072
#define NFREQ 10
#define DISD 60
#define EIN 325              // 2*HH + 9 + DISD
#define NBLK 512             // edge blocks: 4 per graph, 256 edges each

typedef __attribute__((ext_vector_type(8))) short short8;
typedef __attribute__((ext_vector_type(4))) float float4v;

__device__ __forceinline__ float silu_f(float x) {
    return x / (1.0f + __expf(-x));
}

__device__ __forceinline__ uint16_t f2bf(float x) {
    uint32_t u = __builtin_bit_cast(uint32_t, x);
    u += 0x7FFFu + ((u >> 16) & 1u);   // RNE
    return (uint16_t)(u >> 16);
}

// ---------- tiny prep kernels ----------

__global__ void k_lat(const float* __restrict__ lat, float* __restrict__ lat_ip) {
    int b = blockIdx.x, t = threadIdx.x;
    if (t < 9) {
        int i = t / 3, k = t % 3;
        const float* lb = lat + b * 9;
        lat_ip[b*9 + t] = lb[i*3+0]*lb[k*3+0] + lb[i*3+1]*lb[k*3+1] + lb[i*3+2]*lb[k*3+2];
    }
}

// Cc[l][b][c] = eb1[l][c] + sum_k lat_ip[b][k] * ew1[l][256+k][c]
__global__ void k_cc(const float* __restrict__ lat_ip, const float* __restrict__ ew1,
                     const float* __restrict__ eb1, float* __restrict__ Cc) {
    int blk = blockIdx.x;        // l*BB + b
    int l = blk / BB, b = blk % BB;
    int c = threadIdx.x;
    float acc = eb1[l*HH + c];
    #pragma unroll
    for (int k = 0; k < 9; ++k)
        acc += lat_ip[b*9+k] * ew1[((size_t)l*EIN + 2*HH + k)*HH + c];
    Cc[(size_t)blk*HH + c] = acc;
}

__global__ void k_h0(const int* __restrict__ at, const float* __restrict__ emb,
                     float* __restrict__ h) {
    int idx = blockIdx.x * blockDim.x + threadIdx.x;
    int n = idx >> 7, c = idx & 127;
    h[idx] = emb[(at[n]-1)*HH + c];
}

// pack W1d (60x128, pad K to 64) and W2 (128x128) into bf16 MFMA B-fragment order.
// w1p frag idx: ((l*2+ks)*8+nf8)*64+lane ; w2p: ((l*4+ks)*8+nf8)*64+lane
// element ii of lane: B[k = 32*ks + 8*(lane>>4) + ii][n = nf8*16 + (lane&15)]
__global__ void k_wpack(const float* __restrict__ ew1, const float* __restrict__ ew2,
                        uint4* __restrict__ w1p, uint4* __restrict__ w2p) {
    int blk = blockIdx.x;           // 192 = L*48
    int l4 = blk / 48, rem = blk % 48;
    int lane = threadIdx.x;          // 64
    int g = lane >> 4, col = lane & 15;
    uint16_t vals[8];
    if (rem < 16) {
        int ks = rem >> 3, nf8 = rem & 7;
        int n = nf8*16 + col;
        #pragma unroll
        for (int ii = 0; ii < 8; ++ii) {
            int k = 32*ks + 8*g + ii;
            float v = (k < DISD) ? ew1[((size_t)l4*EIN + 2*HH + 9 + k)*HH + n] : 0.0f;
            vals[ii] = f2bf(v);
        }
        uint4 pk = *(const uint4*)vals;
        w1p[((l4*2 + ks)*8 + nf8)*64 + lane] = pk;
    } else {
        int rem2 = rem - 16;
        int ks = rem2 >> 3, nf8 = rem2 & 7;
        int n = nf8*16 + col;
        #pragma unroll
        for (int ii = 0; ii < 8; ++ii) {
            int k = 32*ks + 8*g + ii;
            vals[ii] = f2bf(ew2[((size_t)l4*HH + k)*HH + n]);
        }
        uint4 pk = *(const uint4*)vals;
        w2p[((l4*4 + ks)*8 + nf8)*64 + lane] = pk;
    }
}

// dis -> bf16, pre-packed in per-block MFMA A-fragment order.
// frag idx: ((bid*2+ks)*16+mf16)*64+lane ; elem ii = dis[m=16*mf16+(lane&15)][k=32*ks+8*(lane>>4)+ii]
__global__ __launch_bounds__(256) void k_dis(const float* __restrict__ frac, uint4* __restrict__ disP) {
    __shared__ uint16_t sm[16384];   // [ks][mf16][lane][ii]
    int bid = blockIdx.x;            // 512
    int b = bid >> 2, q = bid & 3;
    int m = threadIdx.x;             // edge within block
    int i = q*8 + (m >> 5), j = m & 31;
    float dx[3];
    #pragma unroll
    for (int d = 0; d < 3; ++d)
        dx[d] = frac[(b*32 + j)*3 + d] - frac[(b*32 + i)*3 + d];
    int mf16 = m >> 4, mlow = m & 15;
    #pragma unroll
    for (int k = 0; k < 64; ++k) {
        float v;
        if (k < 30)       v = __sinf(6.28318530717958647692f * (float)(k % 10) * dx[k / 10]);
        else if (k < 60)  { int kk = k - 30; v = __cosf(6.28318530717958647692f * (float)(kk % 10) * dx[kk / 10]); }
        else              v = 0.0f;
        int ks = k >> 5, g = (k >> 3) & 3, ii = k & 7;
        sm[(((ks*16 + mf16)*64) + g*16 + mlow)*8 + ii] = f2bf(v);
    }
    __syncthreads();
    const uint4* smv = (const uint4*)sm;
    uint4* dst = disP + (size_t)bid * 2048;
    #pragma unroll
    for (int w = 0; w < 8; ++w)
        dst[m + 256*w] = smv[m + 256*w];
}

// fp32: A[n][c] = h[n]@W1a ; Bv[n][c] = h[n]@W1b  (kept fp32 for accuracy of the base term)
__global__ __launch_bounds__(256) void k_ab(const float* __restrict__ h,
                     const float* __restrict__ ew1l,
                     float* __restrict__ A, float* __restrict__ Bv) {
    __shared__ float sm_h[16][HH];
    int n0 = blockIdx.x * 16;
    int t = threadIdx.x;
    for (int idx = t; idx < 16*HH; idx += 256)
        sm_h[idx >> 7][idx & 127] = h[(size_t)n0*HH + idx];
    __syncthreads();
    int half = t >> 7, c = t & 127;
    const float* w = ew1l + (size_t)half*HH*HH;
    float acc[16];
    #pragma unroll
    for (int q = 0; q < 16; ++q) acc[q] = 0.f;
    for (int k = 0; k < HH; ++k) {
        float wv = w[k*HH + c];
        #pragma unroll
        for (int q = 0; q < 16; ++q) acc[q] += sm_h[q][k] * wv;
    }
    float* outp = half ? Bv : A;
    #pragma unroll
    for (int q = 0; q < 16; ++q) outp[(size_t)(n0+q)*HH + c] = acc[q];
}

// ---------- fused edge pipeline + node MLP ----------
// block = quarter graph: 8 src (i) x 32 dst (j) = 256 edges. 4 waves: (wm in M) x (wn in N).
__global__ __launch_bounds__(256) void k_edge(
    const uint4* __restrict__ disP, const uint4* __restrict__ w1p, const uint4* __restrict__ w2p,
    const float* __restrict__ A, const float* __restrict__ Bv,
    const float* __restrict__ Cc_l, const float* __restrict__ b2,
    const float* __restrict__ nw1, const float* __restrict__ nb1,
    const float* __restrict__ nw2, const float* __restrict__ nb2,
    float* __restrict__ h, int l4)
{
    __shared__ char smem[65536];     // s tile 256x128 bf16 (swizzled), reused by node stage
    int bid = blockIdx.x;
    int b = bid >> 2, q = bid & 3;
    int t = threadIdx.x;
    int w = t >> 6, l = t & 63;
    int wm = w >> 1, wn = w & 1;
    int g = l >> 4, rr = l & 15;

    float4v acc[8][4];
    #pragma unroll
    for (int mf = 0; mf < 8; ++mf)
        #pragma unroll
        for (int nf = 0; nf < 4; ++nf)
            acc[mf][nf] = (float4v){0.f, 0.f, 0.f, 0.f};

    // ---- GEMM1: dis(256x64) @ W1d(64x128) ----
    #pragma unroll
    for (int ks = 0; ks < 2; ++ks) {
        short8 wf[4];
        #pragma unroll
        for (int nf = 0; nf < 4; ++nf)
            wf[nf] = *reinterpret_cast<const short8*>(&w1p[(((l4*2 + ks)*8) + wn*4 + nf)*64 + l]);
        #pragma unroll
        for (int mf = 0; mf < 8; ++mf) {
            short8 a = *reinterpret_cast<const short8*>(&disP[(((size_t)bid*2 + ks)*16 + 8*wm + mf)*64 + l]);
            #pragma unroll
            for (int nf = 0; nf < 4; ++nf)
                acc[mf][nf] = __builtin_amdgcn_mfma_f32_16x16x32_bf16(a, wf[nf], acc[mf][nf], 0, 0, 0);
        }
    }

    // ---- base add (fp32) + silu + bf16 -> swizzled LDS ----
    int nbase = 64*wn + rr;
    float ccv[4], av[4][4], bvv[2][4][4];
    #pragma unroll
    for (int nf = 0; nf < 4; ++nf) ccv[nf] = Cc_l[b*HH + nbase + 16*nf];
    #pragma unroll
    for (int p = 0; p < 4; ++p)
        #pragma unroll
        for (int nf = 0; nf < 4; ++nf)
            av[p][nf] = A[(size_t)(b*32 + q*8 + 4*wm + p)*HH + nbase + 16*nf];
    #pragma unroll
    for (int par = 0; par < 2; ++par)
        #pragma unroll
        for (int reg = 0; reg < 4; ++reg)
            #pragma unroll
            for (int nf = 0; nf < 4; ++nf)
                bvv[par][reg][nf] = Bv[(size_t)(b*32 + 16*par + 4*g + reg)*HH + nbase + 16*nf];

    #pragma unroll
    for (int mf = 0; mf < 8; ++mf)
        #pragma unroll
        for (int nf = 0; nf < 4; ++nf)
            #pragma unroll
            for (int reg = 0; reg < 4; ++reg) {
                float x = acc[mf][nf][reg] + av[mf>>1][nf] + bvv[mf&1][reg][nf] + ccv[nf];
                float s = silu_f(x);
                int m = 128*wm + 16*mf + 4*g + reg;
                int n = 64*wn + 16*nf + rr;
                int off = m*256 + ((2*n) ^ ((m & 7) << 4));
                *(uint16_t*)(smem + off) = f2bf(s);
            }
    __syncthreads();

    // ---- GEMM2: s(256x128) @ W2(128x128) ----
    #pragma unroll
    for (int mf = 0; mf < 8; ++mf)
        #pragma unroll
        for (int nf = 0; nf < 4; ++nf)
            acc[mf][nf] = (float4v){0.f, 0.f, 0.f, 0.f};
    #pragma unroll
    for (int ks = 0; ks < 4; ++ks) {
        short8 wf[4];
        #pragma unroll
        for (int nf = 0; nf < 4; ++nf)
            wf[nf] = *reinterpret_cast<const short8*>(&w2p[(((l4*4 + ks)*8) + wn*4 + nf)*64 + l]);
        #pragma unroll
        for (int mf = 0; mf < 8; ++mf) {
            int m = 128*wm + 16*mf + rr;
            int off = m*256 + ((ks*64 + g*16) ^ ((m & 7) << 4));
            short8 a = *reinterpret_cast<const short8*>(smem + off);
            #pragma unroll
            for (int nf = 0; nf < 4; ++nf)
                acc[mf][nf] = __builtin_amdgcn_mfma_f32_16x16x32_bf16(a, wf[nf], acc[mf][nf], 0, 0, 0);
        }
    }

    // ---- +b2, silu, mean over j (32 rows per i) ----
    float b2v[4];
    #pragma unroll
    for (int nf = 0; nf < 4; ++nf) b2v[nf] = b2[nbase + 16*nf];
    float red[4][4];
    #pragma unroll
    for (int p = 0; p < 4; ++p)
        #pragma unroll
        for (int nf = 0; nf < 4; ++nf) {
            float v = 0.f;
            #pragma unroll
            for (int mm = 0; mm < 2; ++mm)
                #pragma unroll
                for (int reg = 0; reg < 4; ++reg)
                    v += silu_f(acc[2*p + mm][nf][reg] + b2v[nf]);
            v += __shfl_xor(v, 16);
            v += __shfl_xor(v, 32);
            red[p][nf] = v * (1.0f / NPGC);
        }
    __syncthreads();   // all LDS reads of s done before overwrite

    // ---- fused node MLP + residual for this block's 8 nodes ----
    float* smf = (float*)smem;       // [8][256]: cols 0..127 = h, 128..255 = agg
    for (int idx = t; idx < 8*2*HH; idx += 256) {
        // stage h rows (only the h half; strided to rows)
    }
    {
        int i0 = t >> 7, c0 = t & 127;
        smf[i0*256 + c0] = h[(size_t)(b*32 + q*8 + i0)*HH + c0];
        smf[(i0+2)*256 + c0] = h[(size_t)(b*32 + q*8 + i0 + 2)*HH + c0];
        smf[(i0+4)*256 + c0] = h[(size_t)(b*32 + q*8 + i0 + 4)*HH + c0];
        smf[(i0+6)*256 + c0] = h[(size_t)(b*32 + q*8 + i0 + 6)*HH + c0];
    }
    if (g == 0) {
        #pragma unroll
        for (int p = 0; p < 4; ++p)
            #pragma unroll
            for (int nf = 0; nf < 4; ++nf)
                smf[(4*wm + p)*256 + HH + 64*wn + 16*nf + rr] = red[p][nf];
    }
    __syncthreads();

    int c = t & 127, ih = t >> 7;
    float u1a[4];
    #pragma unroll
    for (int ii = 0; ii < 4; ++ii) u1a[ii] = nb1[c];
    for (int k = 0; k < 2*HH; ++k) {
        float wv = nw1[k*HH + c];
        #pragma unroll
        for (int ii = 0; ii < 4; ++ii) u1a[ii] += smf[(ih + 2*ii)*256 + k] * wv;
    }
    float* smu = smf + 2048;         // [8][128]
    #pragma unroll
    for (int ii = 0; ii < 4; ++ii) smu[(ih + 2*ii)*HH + c] = silu_f(u1a[ii]);
    __syncthreads();

    float u2a[4];
    #pragma unroll
    for (int ii = 0; ii < 4; ++ii) u2a[ii] = nb2[c];
    for (int k = 0; k < HH; ++k) {
        float wv = nw2[k*HH + c];
        #pragma unroll
        for (int ii = 0; ii < 4; ++ii) u2a[ii] += smu[(ih + 2*ii)*HH + k] * wv;
    }
    #pragma unroll
    for (int ii = 0; ii < 4; ++ii) {
        int node = b*32 + q*8 + ih + 2*ii;
        h[(size_t)node*HH + c] = smf[(ih + 2*ii)*256 + c] + silu_f(u2a[ii]);
    }
}

// graph mean-pool + out projection
__global__ __launch_bounds__(128) void k_pool(const float* __restrict__ h, const float* __restrict__ ow,
                       float* __restrict__ out) {
    __shared__ float sm_g[HH];
    int b = blockIdx.x, c = threadIdx.x;
    float s = 0.f;
    for (int n = 0; n < NPGC; ++n) s += h[(size_t)(b*NPGC+n)*HH + c];
    sm_g[c] = s * (1.0f/NPGC);
    __syncthreads();
    float acc = 0.f;
    for (int k = 0; k < HH; ++k) acc += sm_g[k] * ow[k*HH + c];
    out[(size_t)b*HH + c] = acc;
}

extern "C" void kernel_launch(void* const* d_in, const int* in_sizes, int n_in,
                              void* d_out, int out_size, void* d_ws, size_t ws_size,
                              hipStream_t stream) {
    const int*   atom_types = (const int*)d_in[0];
    const float* frac       = (const float*)d_in[1];
    const float* lat        = (const float*)d_in[2];
    const float* node_emb   = (const float*)d_in[5];
    const float* ew1        = (const float*)d_in[6];
    const float* eb1        = (const float*)d_in[7];
    const float* ew2        = (const float*)d_in[8];
    const float* eb2        = (const float*)d_in[9];
    const float* nw1        = (const float*)d_in[10];
    const float* nb1        = (const float*)d_in[11];
    const float* nw2        = (const float*)d_in[12];
    const float* nb2        = (const float*)d_in[13];
    const float* ow         = (const float*)d_in[14];
    float* out = (float*)d_out;

    char* ws = (char*)d_ws;
    uint4* disP = (uint4*)ws;  ws += (size_t)NBLK*2048*16;      // 16.8 MB
    uint4* w1p  = (uint4*)ws;  ws += (size_t)LL*2*8*64*16;      // 64 KB
    uint4* w2p  = (uint4*)ws;  ws += (size_t)LL*4*8*64*16;      // 128 KB
    float* h    = (float*)ws;  ws += (size_t)NNODE*HH*4;        // 2 MB
    float* A    = (float*)ws;  ws += (size_t)NNODE*HH*4;
    float* Bv   = (float*)ws;  ws += (size_t)NNODE*HH*4;
    float* lat_ip = (float*)ws; ws += 8192;
    float* Cc   = (float*)ws;  ws += (size_t)LL*BB*HH*4;

    k_lat<<<BB, 64, 0, stream>>>(lat, lat_ip);
    k_cc<<<LL*BB, HH, 0, stream>>>(lat_ip, ew1, eb1, Cc);
    k_h0<<<(NNODE*HH)/256, 256, 0, stream>>>(atom_types, node_emb, h);
    k_dis<<<NBLK, 256, 0, stream>>>(frac, disP);
    k_wpack<<<LL*48, 64, 0, stream>>>(ew1, ew2, w1p, w2p);

    for (int l = 0; l < LL; ++l) {
        k_ab<<<NNODE/16, 256, 0, stream>>>(h, ew1 + (size_t)l*EIN*HH, A, Bv);
        k_edge<<<NBLK, 256, 0, stream>>>(disP, w1p, w2p, A, Bv,
                                         Cc + (size_t)l*BB*HH, eb2 + (size_t)l*HH,
                                         nw1 + (size_t)l*2*HH*HH, nb1 + (size_t)l*HH,
                                         nw2 + (size_t)l*HH*HH, nb2 + (size_t)l*HH,
                                         h, l);
    }
    k_pool<<<BB, HH, 0, stream>>>(h, ow, out);
}

// Round 4
// 279.682 us; speedup vs baseline: 2.7710x; 1.3791x over previous
//
#include <hip/hip_runtime.h>
#include <hip/hip_bf16.h>
#include <cstdint>

#define HH 128
#define LL 4
#define BB 128
#define NPGC 32
#define NNODE (BB*NPGC)      // 4096
#define NEDGE (NNODE*NPGC)   // 131072
#define NFREQ 10
#define DISD 60
#define EIN 325              // 2*HH + 9 + DISD
#define NBLK 512             // 4 blocks per graph, 256 edges each

// packed-weight fragment offsets (per layer, in 1KB-frag units)
#define OFF_W1A_HI 0
#define OFF_W1A_LO 32
#define OFF_W1B_HI 64
#define OFF_W1B_LO 96
#define OFF_W1D    128
#define OFF_W2     144
#define OFF_NW1    176
#define OFF_NW2    240
#define FR_PER_L   272

typedef __attribute__((ext_vector_type(8))) short short8;
typedef __attribute__((ext_vector_type(4))) float float4v;

#define MFMA __builtin_amdgcn_mfma_f32_16x16x32_bf16

__device__ __forceinline__ float silu_f(float x) {
#if __has_builtin(__builtin_amdgcn_rcpf)
    return x * __builtin_amdgcn_rcpf(1.0f + __expf(-x));
#else
    return x / (1.0f + __expf(-x));
#endif
}

__device__ __forceinline__ uint16_t f2bf(float x) {
    uint32_t u = __builtin_bit_cast(uint32_t, x);
    u += 0x7FFFu + ((u >> 16) & 1u);   // RNE
    return (uint16_t)(u >> 16);
}

__device__ __forceinline__ short8 ldw(const uint4* wpl, int fidx, int lane) {
    return *reinterpret_cast<const short8*>(&wpl[(size_t)fidx*64 + lane]);
}

// convert 8 consecutive fp32 to hi/lo bf16 pair
__device__ __forceinline__ void cvt8(const float* p, short8& hi, short8& lo) {
    float4v v0 = *(const float4v*)p;
    float4v v1 = *(const float4v*)(p + 4);
    #pragma unroll
    for (int ii = 0; ii < 4; ++ii) {
        uint16_t h0 = f2bf(v0[ii]);
        hi[ii] = (short)h0;
        lo[ii] = (short)f2bf(v0[ii] - __builtin_bit_cast(float, (uint32_t)h0 << 16));
        uint16_t h1 = f2bf(v1[ii]);
        hi[4+ii] = (short)h1;
        lo[4+ii] = (short)f2bf(v1[ii] - __builtin_bit_cast(float, (uint32_t)h1 << 16));
    }
}

// ---------- prep kernels ----------

// lat inner products + Cc[l][b][c] = eb1 + lat_ip @ W1c  (k_lat merged in)
__global__ __launch_bounds__(128) void k_cc(const float* __restrict__ lat,
                     const float* __restrict__ ew1, const float* __restrict__ eb1,
                     float* __restrict__ Cc) {
    __shared__ float lip[9];
    int blk = blockIdx.x;            // l*BB + b
    int l = blk >> 7, b = blk & 127;
    int c = threadIdx.x;
    if (c < 9) {
        int i = c / 3, k = c % 3;
        const float* lb = lat + b*9;
        lip[c] = lb[i*3]*lb[k*3] + lb[i*3+1]*lb[k*3+1] + lb[i*3+2]*lb[k*3+2];
    }
    __syncthreads();
    float acc = eb1[l*HH + c];
    #pragma unroll
    for (int k = 0; k < 9; ++k)
        acc += lip[k] * ew1[((size_t)l*EIN + 2*HH + k)*HH + c];
    Cc[(size_t)blk*HH + c] = acc;
}

__global__ void k_h0(const int* __restrict__ at, const float* __restrict__ emb,
                     float* __restrict__ h) {
    int idx = blockIdx.x * blockDim.x + threadIdx.x;
    int n = idx >> 7;
    h[idx] = emb[(at[n]-1)*HH + (idx & 127)];
}

// pack all per-layer weights into bf16 MFMA B-fragment order (hi/lo for W1a,W1b)
__global__ void k_wpack(const float* __restrict__ ew1, const float* __restrict__ ew2,
                        const float* __restrict__ nw1, const float* __restrict__ nw2,
                        uint4* __restrict__ wp) {
    int bidx = blockIdx.x;          // LL*26
    int l = bidx / 26, j = bidx % 26;
    int lane = threadIdx.x;          // 64
    int g = lane >> 4, col = lane & 15;
    const float* src; int ks, K, base; bool hilo = false; int baselo = 0;
    if (j < 4)       { ks = j;      src = ew1 + (size_t)l*EIN*HH;              K = 128;  hilo = true; base = OFF_W1A_HI; baselo = OFF_W1A_LO; }
    else if (j < 8)  { ks = j - 4;  src = ew1 + ((size_t)l*EIN + HH)*HH;       K = 128;  hilo = true; base = OFF_W1B_HI; baselo = OFF_W1B_LO; }
    else if (j < 10) { ks = j - 8;  src = ew1 + ((size_t)l*EIN + 2*HH + 9)*HH; K = DISD; base = OFF_W1D; }
    else if (j < 14) { ks = j - 10; src = ew2 + (size_t)l*HH*HH;               K = 128;  base = OFF_W2; }
    else if (j < 22) { ks = j - 14; src = nw1 + (size_t)l*2*HH*HH;             K = 256;  base = OFF_NW1; }
    else             { ks = j - 22; src = nw2 + (size_t)l*HH*HH;               K = 128;  base = OFF_NW2; }
    for (int nf = 0; nf < 8; ++nf) {
        int n = nf*16 + col;
        uint16_t hi[8], lo[8];
        #pragma unroll
        for (int ii = 0; ii < 8; ++ii) {
            int k = 32*ks + 8*g + ii;
            float v = (k < K) ? src[(size_t)k*HH + n] : 0.0f;
            uint16_t h0 = f2bf(v);
            hi[ii] = h0;
            lo[ii] = f2bf(v - __builtin_bit_cast(float, (uint32_t)h0 << 16));
        }
        wp[((size_t)l*FR_PER_L + base + ks*8 + nf)*64 + lane] = *(const uint4*)hi;
        if (hilo)
            wp[((size_t)l*FR_PER_L + baselo + ks*8 + nf)*64 + lane] = *(const uint4*)lo;
    }
}

// dis -> bf16, pre-packed in per-block MFMA A-fragment order (verified round 2)
__global__ __launch_bounds__(256) void k_dis(const float* __restrict__ frac, uint4* __restrict__ disP) {
    __shared__ uint16_t sm[16384];
    int bid = blockIdx.x;            // 512
    int b = bid >> 2, q = bid & 3;
    int m = threadIdx.x;
    int i = q*8 + (m >> 5), j = m & 31;
    float dx[3];
    #pragma unroll
    for (int d = 0; d < 3; ++d)
        dx[d] = frac[(b*32 + j)*3 + d] - frac[(b*32 + i)*3 + d];
    int mf16 = m >> 4, mlow = m & 15;
    #pragma unroll
    for (int k = 0; k < 64; ++k) {
        float v;
        if (k < 30)       v = __sinf(6.28318530717958647692f * (float)(k % 10) * dx[k / 10]);
        else if (k < 60)  { int kk = k - 30; v = __cosf(6.28318530717958647692f * (float)(kk % 10) * dx[kk / 10]); }
        else              v = 0.0f;
        int ks = k >> 5, g = (k >> 3) & 3, ii = k & 7;
        sm[(((ks*16 + mf16)*64) + g*16 + mlow)*8 + ii] = f2bf(v);
    }
    __syncthreads();
    const uint4* smv = (const uint4*)sm;
    uint4* dst = disP + (size_t)bid * 2048;
    #pragma unroll
    for (int w = 0; w < 8; ++w)
        dst[m + 256*w] = smv[m + 256*w];
}

// ---------- the fused layer kernel ----------
// block = (b,q): src rows i in [q*8, q*8+8), all 32 dst. 4 waves.
__global__ __launch_bounds__(256) void k_layer(
    const float* __restrict__ h_in, float* __restrict__ h_out,
    const uint4* __restrict__ disP, const uint4* __restrict__ wpl,
    const float* __restrict__ Cc_l, const float* __restrict__ b2,
    const float* __restrict__ nb1, const float* __restrict__ nb2)
{
    __shared__ uint4 smem4[3632];                 // 58112 B
    char* smem = (char*)smem4;
    char* sS = smem;                              // 32 KB s half-tile, rows*256B, XOR-swizzled
    float* BvL     = (float*)(smem + 32768);      // [32][132] f32 (phase A)
    uint16_t* hn   = (uint16_t*)(smem + 32768);   // [8][256] bf16 (node phase, overlays BvL)
    uint16_t* u1L  = (uint16_t*)(smem + 32768 + 4096);  // [8][128] bf16
    float* hres    = (float*)(smem + 32768 + 6144);     // [8][132] f32
    float* AL      = (float*)(smem + 49664);      // [8][132] f32
    float* aggL    = (float*)(smem + 53888);      // [8][132] f32

    int bid = blockIdx.x;
    int b = bid >> 2, q = bid & 3;
    int t = threadIdx.x;
    int w = t >> 6, l = t & 63;
    int wm = w >> 1, wn = w & 1;
    int g = l >> 4, rr = l & 15;

    // ---- phase 0: Bv = h@W1b (32 rows), A = h@W1a (8 src rows), hi/lo-split MFMA ----
    float4v bacc[4], aacc[2];
    #pragma unroll
    for (int nf = 0; nf < 4; ++nf) bacc[nf] = (float4v){0.f,0.f,0.f,0.f};
    #pragma unroll
    for (int nfl = 0; nfl < 2; ++nfl) aacc[nfl] = (float4v){0.f,0.f,0.f,0.f};

    #pragma unroll
    for (int ks = 0; ks < 4; ++ks) {
        short8 hhi, hlo;
        cvt8(h_in + (size_t)(b*32 + 16*wm + rr)*HH + 32*ks + 8*g, hhi, hlo);
        #pragma unroll
        for (int nf = 0; nf < 4; ++nf) {
            short8 whi = ldw(wpl, OFF_W1B_HI + ks*8 + 4*wn + nf, l);
            short8 wlo = ldw(wpl, OFF_W1B_LO + ks*8 + 4*wn + nf, l);
            bacc[nf] = MFMA(hhi, whi, bacc[nf], 0, 0, 0);
            bacc[nf] = MFMA(hlo, whi, bacc[nf], 0, 0, 0);
            bacc[nf] = MFMA(hhi, wlo, bacc[nf], 0, 0, 0);
        }
        short8 ahi, alo;
        cvt8(h_in + (size_t)(b*32 + q*8 + (rr & 7))*HH + 32*ks + 8*g, ahi, alo);
        #pragma unroll
        for (int nfl = 0; nfl < 2; ++nfl) {
            int nf8 = 4*wn + 2*wm + nfl;
            short8 whi = ldw(wpl, OFF_W1A_HI + ks*8 + nf8, l);
            short8 wlo = ldw(wpl, OFF_W1A_LO + ks*8 + nf8, l);
            aacc[nfl] = MFMA(ahi, whi, aacc[nfl], 0, 0, 0);
            aacc[nfl] = MFMA(alo, whi, aacc[nfl], 0, 0, 0);
            aacc[nfl] = MFMA(ahi, wlo, aacc[nfl], 0, 0, 0);
        }
    }
    #pragma unroll
    for (int nf = 0; nf < 4; ++nf)
        #pragma unroll
        for (int r = 0; r < 4; ++r)
            BvL[(16*wm + 4*g + r)*132 + 64*wn + 16*nf + rr] = bacc[nf][r];
    if (g < 2)
        #pragma unroll
        for (int nfl = 0; nfl < 2; ++nfl)
            #pragma unroll
            for (int r = 0; r < 4; ++r)
                AL[(4*g + r)*132 + 64*wn + 32*wm + 16*nfl + rr] = aacc[nfl][r];
    __syncthreads();

    float ccv[4], b2v[4];
    #pragma unroll
    for (int nf = 0; nf < 4; ++nf) {
        ccv[nf] = Cc_l[b*HH + 64*wn + 16*nf + rr];
        b2v[nf] = b2[64*wn + 16*nf + rr];
    }

    // ---- two M-passes of 128 edges: GEMM1 + base + silu -> GEMM2 -> j-mean ----
    #pragma unroll
    for (int p = 0; p < 2; ++p) {
        float4v acc[4][4];
        #pragma unroll
        for (int mf = 0; mf < 4; ++mf)
            #pragma unroll
            for (int nf = 0; nf < 4; ++nf)
                acc[mf][nf] = (float4v){0.f,0.f,0.f,0.f};
        // GEMM1: dis @ W1d
        #pragma unroll
        for (int ks = 0; ks < 2; ++ks) {
            short8 wf[4];
            #pragma unroll
            for (int nf = 0; nf < 4; ++nf)
                wf[nf] = ldw(wpl, OFF_W1D + ks*8 + 4*wn + nf, l);
            #pragma unroll
            for (int mf = 0; mf < 4; ++mf) {
                int mf16 = 8*p + 4*wm + mf;
                short8 a = *reinterpret_cast<const short8*>(&disP[((size_t)(bid*2 + ks)*16 + mf16)*64 + l]);
                #pragma unroll
                for (int nf = 0; nf < 4; ++nf)
                    acc[mf][nf] = MFMA(a, wf[nf], acc[mf][nf], 0, 0, 0);
            }
        }
        // base add + silu -> sS (swizzled bf16)
        #pragma unroll
        for (int mf = 0; mf < 4; ++mf) {
            int il = 4*p + 2*wm + (mf >> 1);
            #pragma unroll
            for (int nf = 0; nf < 4; ++nf) {
                int n = 64*wn + 16*nf + rr;
                float av = AL[il*132 + n];
                #pragma unroll
                for (int r = 0; r < 4; ++r) {
                    int mrel = 16*mf + 4*g + r;
                    int m_loc = 64*wm + mrel;
                    int jj = mrel & 31;
                    float x = acc[mf][nf][r] + av + BvL[jj*132 + n] + ccv[nf];
                    int off = m_loc*256 + ((2*n) ^ ((m_loc & 7) << 4));
                    *(uint16_t*)(sS + off) = f2bf(silu_f(x));
                }
            }
        }
        __syncthreads();
        // GEMM2: s @ W2
        #pragma unroll
        for (int mf = 0; mf < 4; ++mf)
            #pragma unroll
            for (int nf = 0; nf < 4; ++nf)
                acc[mf][nf] = (float4v){0.f,0.f,0.f,0.f};
        #pragma unroll
        for (int ks = 0; ks < 4; ++ks) {
            short8 wf[4];
            #pragma unroll
            for (int nf = 0; nf < 4; ++nf)
                wf[nf] = ldw(wpl, OFF_W2 + ks*8 + 4*wn + nf, l);
            #pragma unroll
            for (int mf = 0; mf < 4; ++mf) {
                int m_loc = 64*wm + 16*mf + rr;
                int off = m_loc*256 + ((64*ks + 16*g) ^ ((m_loc & 7) << 4));
                short8 a = *reinterpret_cast<const short8*>(sS + off);
                #pragma unroll
                for (int nf = 0; nf < 4; ++nf)
                    acc[mf][nf] = MFMA(a, wf[nf], acc[mf][nf], 0, 0, 0);
            }
        }
        // +b2, silu, mean over the 32 j
        #pragma unroll
        for (int u = 0; u < 2; ++u)
            #pragma unroll
            for (int nf = 0; nf < 4; ++nf) {
                float v = 0.f;
                #pragma unroll
                for (int mm = 0; mm < 2; ++mm)
                    #pragma unroll
                    for (int r = 0; r < 4; ++r)
                        v += silu_f(acc[2*u + mm][nf][r] + b2v[nf]);
                v += __shfl_xor(v, 16);
                v += __shfl_xor(v, 32);
                if (g == 0)
                    aggL[(4*p + 2*wm + u)*132 + 64*wn + 16*nf + rr] = v * (1.0f/32.0f);
            }
        __syncthreads();
    }

    // ---- node MLP for this block's 8 nodes (MFMA, bf16) ----
    {
        int i = t >> 5, cq = t & 31;
        const float* hp = h_in + (size_t)(b*32 + q*8 + i)*HH + cq*4;
        float4v hv = *(const float4v*)hp;
        uint16_t pk[4];
        #pragma unroll
        for (int z = 0; z < 4; ++z) { hres[i*132 + cq*4 + z] = hv[z]; pk[z] = f2bf(hv[z]); }
        *(uint64_t*)&hn[i*256 + cq*4] = *(const uint64_t*)pk;
        #pragma unroll
        for (int z = 0; z < 4; ++z) pk[z] = f2bf(aggL[i*132 + cq*4 + z]);
        *(uint64_t*)&hn[i*256 + 128 + cq*4] = *(const uint64_t*)pk;
    }
    __syncthreads();

    float4v uacc[2];
    #pragma unroll
    for (int nfl = 0; nfl < 2; ++nfl) uacc[nfl] = (float4v){0.f,0.f,0.f,0.f};
    #pragma unroll
    for (int ks = 0; ks < 8; ++ks) {
        short8 a = *reinterpret_cast<const short8*>(&hn[(rr & 7)*256 + 32*ks + 8*g]);
        #pragma unroll
        for (int nfl = 0; nfl < 2; ++nfl)
            uacc[nfl] = MFMA(a, ldw(wpl, OFF_NW1 + ks*8 + 2*w + nfl, l), uacc[nfl], 0, 0, 0);
    }
    if (g < 2)
        #pragma unroll
        for (int nfl = 0; nfl < 2; ++nfl)
            #pragma unroll
            for (int r = 0; r < 4; ++r) {
                int col = (2*w + nfl)*16 + rr;
                u1L[(4*g + r)*128 + col] = f2bf(silu_f(uacc[nfl][r] + nb1[col]));
            }
    __syncthreads();

    float4v vacc[2];
    #pragma unroll
    for (int nfl = 0; nfl < 2; ++nfl) vacc[nfl] = (float4v){0.f,0.f,0.f,0.f};
    #pragma unroll
    for (int ks = 0; ks < 4; ++ks) {
        short8 a = *reinterpret_cast<const short8*>(&u1L[(rr & 7)*128 + 32*ks + 8*g]);
        #pragma unroll
        for (int nfl = 0; nfl < 2; ++nfl)
            vacc[nfl] = MFMA(a, ldw(wpl, OFF_NW2 + ks*8 + 2*w + nfl, l), vacc[nfl], 0, 0, 0);
    }
    if (g < 2)
        #pragma unroll
        for (int nfl = 0; nfl < 2; ++nfl)
            #pragma unroll
            for (int r = 0; r < 4; ++r) {
                int row = 4*g + r, col = (2*w + nfl)*16 + rr;
                h_out[(size_t)(b*32 + q*8 + row)*HH + col] =
                    hres[row*132 + col] + silu_f(vacc[nfl][r] + nb2[col]);
            }
}

// graph mean-pool + out projection
__global__ __launch_bounds__(128) void k_pool(const float* __restrict__ h, const float* __restrict__ ow,
                       float* __restrict__ out) {
    __shared__ float sm_g[HH];
    int b = blockIdx.x, c = threadIdx.x;
    float s = 0.f;
    for (int n = 0; n < NPGC; ++n) s += h[(size_t)(b*NPGC+n)*HH + c];
    sm_g[c] = s * (1.0f/NPGC);
    __syncthreads();
    float acc = 0.f;
    for (int k = 0; k < HH; ++k) acc += sm_g[k] * ow[k*HH + c];
    out[(size_t)b*HH + c] = acc;
}

extern "C" void kernel_launch(void* const* d_in, const int* in_sizes, int n_in,
                              void* d_out, int out_size, void* d_ws, size_t ws_size,
                              hipStream_t stream) {
    const int*   atom_types = (const int*)d_in[0];
    const float* frac       = (const float*)d_in[1];
    const float* lat        = (const float*)d_in[2];
    const float* node_emb   = (const float*)d_in[5];
    const float* ew1        = (const float*)d_in[6];
    const float* eb1        = (const float*)d_in[7];
    const float* ew2        = (const float*)d_in[8];
    const float* eb2        = (const float*)d_in[9];
    const float* nw1        = (const float*)d_in[10];
    const float* nb1        = (const float*)d_in[11];
    const float* nw2        = (const float*)d_in[12];
    const float* nb2        = (const float*)d_in[13];
    const float* ow         = (const float*)d_in[14];
    float* out = (float*)d_out;

    char* ws = (char*)d_ws;
    uint4* disP = (uint4*)ws; ws += (size_t)NBLK*2048*16;          // 16.8 MB
    uint4* wp   = (uint4*)ws; ws += (size_t)LL*FR_PER_L*64*16;     // 1.1 MB
    float* hA   = (float*)ws; ws += (size_t)NNODE*HH*4;            // 2 MB
    float* hB   = (float*)ws; ws += (size_t)NNODE*HH*4;            // 2 MB
    float* Cc   = (float*)ws; ws += (size_t)LL*BB*HH*4;            // 256 KB

    k_cc<<<LL*BB, 128, 0, stream>>>(lat, ew1, eb1, Cc);
    k_h0<<<(NNODE*HH)/256, 256, 0, stream>>>(atom_types, node_emb, hA);
    k_dis<<<NBLK, 256, 0, stream>>>(frac, disP);
    k_wpack<<<LL*26, 64, 0, stream>>>(ew1, ew2, nw1, nw2, wp);

    float* hin = hA; float* hout = hB;
    for (int l = 0; l < LL; ++l) {
        k_layer<<<NBLK, 256, 0, stream>>>(hin, hout, disP, wp + (size_t)l*FR_PER_L*64,
                                          Cc + (size_t)l*BB*HH, eb2 + (size_t)l*HH,
                                          nb1 + (size_t)l*HH, nb2 + (size_t)l*HH);
        float* tmp = hin; hin = hout; hout = tmp;
    }
    k_pool<<<BB, HH, 0, stream>>>(hin, ow, out);
}

// Round 5
// 243.195 us; speedup vs baseline: 3.1868x; 1.1500x over previous
//
#include <hip/hip_runtime.h>
#include <hip/hip_bf16.h>
#include <cstdint>

#define HH 128
#define LL 4
#define BB 128
#define NNODE 4096
#define EIN 325
#define NBLK 1024            // block = (b, q4): 4 src x 32 dst = 128 edges

// packed-weight fragment offsets (per layer, 1KB frags)
#define OFF_W1  0            // [W1a(128);W1b(128);W1d(60)+pad4] : 10 ks x 8 nf = 80
#define OFF_W2  80           // 4 ks x 8 nf = 32
#define OFF_NW1 112          // 8 ks x 8 nf = 64
#define OFF_NW2 176          // 4 ks x 8 nf = 32
#define FR_PER_L 208

typedef __attribute__((ext_vector_type(8))) short short8;
typedef __attribute__((ext_vector_type(4))) float float4v;

#define MFMA __builtin_amdgcn_mfma_f32_16x16x32_bf16

__device__ __forceinline__ float silu_f(float x) {
    return x / (1.0f + __expf(-x));
}

__device__ __forceinline__ uint16_t f2bf(float x) {
    uint32_t u = __builtin_bit_cast(uint32_t, x);
    u += 0x7FFFu + ((u >> 16) & 1u);   // RNE
    return (uint16_t)(u >> 16);
}

__device__ __forceinline__ short8 ldw(const uint4* wpl, int fidx, int lane) {
    return *reinterpret_cast<const short8*>(&wpl[(size_t)fidx*64 + lane]);
}

// ---------- fused prep kernel: roles by blockIdx ----------
// [0,1024): dis pack   [1024,1128): weight pack   [1128,1640): Cc   [1640,2152): h0
__global__ __launch_bounds__(256) void k_prep(
    const int* __restrict__ at, const float* __restrict__ frac,
    const float* __restrict__ lat, const float* __restrict__ emb,
    const float* __restrict__ ew1, const float* __restrict__ eb1,
    const float* __restrict__ ew2, const float* __restrict__ nw1,
    const float* __restrict__ nw2,
    uint4* __restrict__ disP, uint4* __restrict__ wp,
    float* __restrict__ h0, float* __restrict__ Cc)
{
    __shared__ uint16_t sm[8192];    // 16KB; cc role aliases first bytes as float[9]
    int gid = blockIdx.x, t = threadIdx.x;

    if (gid < 1024) {
        // ---- dis: 128 edges -> 16 MFMA A-frags (2 ks x 8 mtiles) ----
        #pragma unroll
        for (int z = 0; z < 4; ++z) ((uint4*)sm)[t + 256*z] = uint4{0,0,0,0};
        __syncthreads();
        int b = gid >> 3, q4 = gid & 7;
        int e2 = t >> 1, half = t & 1;
        int i = q4*4 + (e2 >> 5), j = e2 & 31;
        float dx[3];
        #pragma unroll
        for (int d = 0; d < 3; ++d)
            dx[d] = frac[(b*32 + j)*3 + d] - frac[(b*32 + i)*3 + d];
        int T = e2 >> 4, rr = e2 & 15;
        #pragma unroll
        for (int kk = 0; kk < 30; ++kk) {
            int d = kk / 10, f = kk % 10;
            float ang = 6.28318530717958647692f * (float)f * dx[d];
            float v = half ? __cosf(ang) : __sinf(ang);
            int k = kk + 30*half;
            int ks = k >> 5, g = (k >> 3) & 3, ii = k & 7;
            sm[((ks*8 + T)*64 + g*16 + rr)*8 + ii] = f2bf(v);
        }
        __syncthreads();
        uint4* dst = disP + (size_t)gid * 1024;
        const uint4* smv = (const uint4*)sm;
        #pragma unroll
        for (int z = 0; z < 4; ++z) dst[t + 256*z] = smv[t + 256*z];
    } else if (gid < 1128) {
        // ---- weight pack ----
        int jidx = gid - 1024;
        int lay = jidx / 26, jj = jidx % 26;
        int wv = t >> 6, lane = t & 63, g = lane >> 4, col = lane & 15;
        int ks, base, type;
        if (jj < 10)      { ks = jj;      base = OFF_W1;  type = 0; }
        else if (jj < 14) { ks = jj - 10; base = OFF_W2;  type = 1; }
        else if (jj < 22) { ks = jj - 14; base = OFF_NW1; type = 2; }
        else              { ks = jj - 22; base = OFF_NW2; type = 3; }
        for (int nn = 0; nn < 2; ++nn) {
            int nf = 2*wv + nn;
            int n = nf*16 + col;
            uint16_t vals[8];
            #pragma unroll
            for (int ii = 0; ii < 8; ++ii) {
                int gk = 32*ks + 8*g + ii;
                float v = 0.f;
                if (type == 0) {
                    if (gk < 256)       v = ew1[((size_t)lay*EIN + gk)*HH + n];
                    else if (gk < 316)  v = ew1[((size_t)lay*EIN + gk + 9)*HH + n];
                } else if (type == 1)   v = ew2[((size_t)lay*HH + gk)*HH + n];
                else if (type == 2)     v = nw1[((size_t)lay*2*HH + gk)*HH + n];
                else                    v = nw2[((size_t)lay*HH + gk)*HH + n];
                vals[ii] = f2bf(v);
            }
            wp[((size_t)lay*FR_PER_L + base + ks*8 + nf)*64 + lane] = *(const uint4*)vals;
        }
    } else if (gid < 1640) {
        // ---- Cc = eb1 + lat_ip @ W1c ----
        float* lip = (float*)sm;
        int blk = gid - 1128;
        int lay = blk >> 7, b = blk & 127;
        if (t < 9) {
            int i = t / 3, k2 = t % 3;
            const float* lb = lat + b*9;
            lip[t] = lb[i*3]*lb[k2*3] + lb[i*3+1]*lb[k2*3+1] + lb[i*3+2]*lb[k2*3+2];
        }
        __syncthreads();
        if (t < 128) {
            float acc = eb1[lay*HH + t];
            #pragma unroll
            for (int k = 0; k < 9; ++k)
                acc += lip[k] * ew1[((size_t)lay*EIN + 2*HH + k)*HH + t];
            Cc[(size_t)blk*HH + t] = acc;
        }
    } else {
        // ---- h0 gather (vectorized) ----
        int idx = (gid - 1640)*256 + t;    // < 131072
        int n = idx >> 5, cq = idx & 31;
        float4v v = *(const float4v*)&emb[((size_t)(at[n]-1))*HH + cq*4];
        *(float4v*)&h0[(size_t)n*HH + cq*4] = v;
    }
}

// ---------- fused layer kernel ----------
// block = (b,q4): src nodes b*32+q4*4+{0..3}, all 32 dst. M=128 edges. 4 waves (2x2).
__global__ __launch_bounds__(256) void k_layer(
    const float* __restrict__ h_in, float* __restrict__ h_out,
    const uint4* __restrict__ disP, const uint4* __restrict__ wpl,
    const float* __restrict__ Cc_l, const float* __restrict__ b2,
    const float* __restrict__ nb1, const float* __restrict__ nb2)
{
    __shared__ char smem[51200];
    char* hHi = smem;                            // [32] rows x 256B bf16, XOR-swizzled
    char* hLo = smem + 8192;
    char* sS  = smem + 16384;                    // [128] rows x 256B bf16, XOR-swizzled
    uint16_t* aggB = (uint16_t*)(smem + 49152);  // [4][128] bf16
    uint16_t* u1B  = (uint16_t*)(smem + 50176);  // [4][128] bf16

    int bid = blockIdx.x;
    int b = bid >> 3, q4 = bid & 7;
    int t = threadIdx.x;
    int w = t >> 6, l = t & 63;
    int wm = w >> 1, wn = w & 1;
    int g = l >> 4, rr = l & 15;

    // ---- stage h tile (32 rows) hi/lo bf16, swizzled ----
    {
        int row = t >> 3, cz = (t & 7) * 16;
        const float* hp = h_in + (size_t)(b*32 + row)*HH + cz;
        uint16_t phi[16], plo[16];
        #pragma unroll
        for (int z = 0; z < 16; z += 4) {
            float4v v = *(const float4v*)(hp + z);
            #pragma unroll
            for (int y = 0; y < 4; ++y) {
                uint16_t hv = f2bf(v[y]);
                phi[z+y] = hv;
                plo[z+y] = f2bf(v[y] - __builtin_bit_cast(float, (uint32_t)hv << 16));
            }
        }
        int sw = (row & 7) << 4;
        int base = row * 256;
        *(uint4*)(hHi + base + ((2*cz) ^ sw))      = *(const uint4*)&phi[0];
        *(uint4*)(hHi + base + ((2*cz + 16) ^ sw)) = *(const uint4*)&phi[8];
        *(uint4*)(hLo + base + ((2*cz) ^ sw))      = *(const uint4*)&plo[0];
        *(uint4*)(hLo + base + ((2*cz + 16) ^ sw)) = *(const uint4*)&plo[8];
    }
    __syncthreads();

    float ccv[4], b2v[4];
    #pragma unroll
    for (int nf = 0; nf < 4; ++nf) {
        ccv[nf] = Cc_l[b*HH + 64*wn + 16*nf + rr];
        b2v[nf] = b2[64*wn + 16*nf + rr];
    }

    float4v acc[4][4];
    #pragma unroll
    for (int mf = 0; mf < 4; ++mf)
        #pragma unroll
        for (int nf = 0; nf < 4; ++nf)
            acc[mf][nf] = (float4v){ccv[nf], ccv[nf], ccv[nf], ccv[nf]};

    // ---- GEMM1: K = [h_src 4ks | h_dst 4ks | dis 2ks]; hi+lo A-terms for h ----
    #pragma unroll
    for (int ks = 0; ks < 10; ++ks) {
        short8 wf[4];
        #pragma unroll
        for (int nf = 0; nf < 4; ++nf)
            wf[nf] = ldw(wpl, OFF_W1 + ks*8 + 4*wn + nf, l);
        #pragma unroll
        for (int mf = 0; mf < 4; ++mf) {
            int T = 4*wm + mf;
            if (ks < 4) {            // h_src: broadcast row
                int R = q4*4 + (T >> 1);
                int off = R*256 + ((64*ks + 16*g) ^ ((R & 7) << 4));
                short8 ahi = *(const short8*)(hHi + off);
                short8 alo = *(const short8*)(hLo + off);
                #pragma unroll
                for (int nf = 0; nf < 4; ++nf) {
                    acc[mf][nf] = MFMA(ahi, wf[nf], acc[mf][nf], 0, 0, 0);
                    acc[mf][nf] = MFMA(alo, wf[nf], acc[mf][nf], 0, 0, 0);
                }
            } else if (ks < 8) {     // h_dst: per-lane row
                int R = ((T & 1) << 4) + rr;
                int off = R*256 + ((64*(ks-4) + 16*g) ^ ((R & 7) << 4));
                short8 ahi = *(const short8*)(hHi + off);
                short8 alo = *(const short8*)(hLo + off);
                #pragma unroll
                for (int nf = 0; nf < 4; ++nf) {
                    acc[mf][nf] = MFMA(ahi, wf[nf], acc[mf][nf], 0, 0, 0);
                    acc[mf][nf] = MFMA(alo, wf[nf], acc[mf][nf], 0, 0, 0);
                }
            } else {                 // dis (pre-packed A-frags)
                short8 a = *(const short8*)&disP[((size_t)(bid*2 + (ks-8))*8 + T)*64 + l];
                #pragma unroll
                for (int nf = 0; nf < 4; ++nf)
                    acc[mf][nf] = MFMA(a, wf[nf], acc[mf][nf], 0, 0, 0);
            }
        }
    }

    // ---- silu -> sS (swizzled bf16) ----
    #pragma unroll
    for (int mf = 0; mf < 4; ++mf) {
        int T = 4*wm + mf;
        #pragma unroll
        for (int nf = 0; nf < 4; ++nf) {
            int n = 64*wn + 16*nf + rr;
            #pragma unroll
            for (int r = 0; r < 4; ++r) {
                int m = 16*T + 4*g + r;
                *(uint16_t*)(sS + m*256 + ((2*n) ^ ((m & 7) << 4))) = f2bf(silu_f(acc[mf][nf][r]));
            }
        }
    }
    __syncthreads();

    // ---- GEMM2: s(128x128) @ W2 ----
    #pragma unroll
    for (int mf = 0; mf < 4; ++mf)
        #pragma unroll
        for (int nf = 0; nf < 4; ++nf)
            acc[mf][nf] = (float4v){0.f, 0.f, 0.f, 0.f};
    #pragma unroll
    for (int ks = 0; ks < 4; ++ks) {
        short8 wf[4];
        #pragma unroll
        for (int nf = 0; nf < 4; ++nf)
            wf[nf] = ldw(wpl, OFF_W2 + ks*8 + 4*wn + nf, l);
        #pragma unroll
        for (int mf = 0; mf < 4; ++mf) {
            int m = 16*(4*wm + mf) + rr;
            short8 a = *(const short8*)(sS + m*256 + ((64*ks + 16*g) ^ ((m & 7) << 4)));
            #pragma unroll
            for (int nf = 0; nf < 4; ++nf)
                acc[mf][nf] = MFMA(a, wf[nf], acc[mf][nf], 0, 0, 0);
        }
    }

    // ---- +b2, silu, mean over 32 j -> aggB bf16 ----
    #pragma unroll
    for (int u = 0; u < 2; ++u) {            // i_loc = 2*wm + u
        #pragma unroll
        for (int nf = 0; nf < 4; ++nf) {
            float v = 0.f;
            #pragma unroll
            for (int mm = 0; mm < 2; ++mm)
                #pragma unroll
                for (int r = 0; r < 4; ++r)
                    v += silu_f(acc[2*u + mm][nf][r] + b2v[nf]);
            v += __shfl_xor(v, 16);
            v += __shfl_xor(v, 32);
            if (g == 0)
                aggB[(2*wm + u)*128 + 64*wn + 16*nf + rr] = f2bf(v * (1.0f/32.0f));
        }
    }
    __syncthreads();

    // ---- node MLP1: [h | agg] @ NW1 ----
    float4v uacc[2];
    #pragma unroll
    for (int nfl = 0; nfl < 2; ++nfl) uacc[nfl] = (float4v){0.f, 0.f, 0.f, 0.f};
    #pragma unroll
    for (int ks = 0; ks < 8; ++ks) {
        short8 a;
        if (ks < 4) {
            int R = q4*4 + (rr & 3);
            a = *(const short8*)(hHi + R*256 + ((64*ks + 16*g) ^ ((R & 7) << 4)));
        } else {
            a = *(const short8*)&aggB[(rr & 3)*128 + 32*(ks - 4) + 8*g];
        }
        #pragma unroll
        for (int nfl = 0; nfl < 2; ++nfl)
            uacc[nfl] = MFMA(a, ldw(wpl, OFF_NW1 + ks*8 + 2*w + nfl, l), uacc[nfl], 0, 0, 0);
    }
    if (g == 0) {
        #pragma unroll
        for (int nfl = 0; nfl < 2; ++nfl)
            #pragma unroll
            for (int r = 0; r < 4; ++r) {
                int col = (2*w + nfl)*16 + rr;
                u1B[r*128 + col] = f2bf(silu_f(uacc[nfl][r] + nb1[col]));
            }
    }
    __syncthreads();

    // ---- node MLP2 + residual ----
    float4v vacc[2];
    #pragma unroll
    for (int nfl = 0; nfl < 2; ++nfl) vacc[nfl] = (float4v){0.f, 0.f, 0.f, 0.f};
    #pragma unroll
    for (int ks = 0; ks < 4; ++ks) {
        short8 a = *(const short8*)&u1B[(rr & 3)*128 + 32*ks + 8*g];
        #pragma unroll
        for (int nfl = 0; nfl < 2; ++nfl)
            vacc[nfl] = MFMA(a, ldw(wpl, OFF_NW2 + ks*8 + 2*w + nfl, l), vacc[nfl], 0, 0, 0);
    }
    if (g == 0) {
        #pragma unroll
        for (int nfl = 0; nfl < 2; ++nfl)
            #pragma unroll
            for (int r = 0; r < 4; ++r) {
                int col = (2*w + nfl)*16 + rr;
                size_t node = (size_t)(b*32 + q4*4 + r);
                h_out[node*HH + col] = h_in[node*HH + col] + silu_f(vacc[nfl][r] + nb2[col]);
            }
    }
}

// graph mean-pool + out projection
__global__ __launch_bounds__(128) void k_pool(const float* __restrict__ h, const float* __restrict__ ow,
                       float* __restrict__ out) {
    __shared__ float sm_g[HH];
    int b = blockIdx.x, c = threadIdx.x;
    float s = 0.f;
    for (int n = 0; n < 32; ++n) s += h[(size_t)(b*32 + n)*HH + c];
    sm_g[c] = s * (1.0f/32.0f);
    __syncthreads();
    float acc = 0.f;
    for (int k = 0; k < HH; ++k) acc += sm_g[k] * ow[k*HH + c];
    out[(size_t)b*HH + c] = acc;
}

extern "C" void kernel_launch(void* const* d_in, const int* in_sizes, int n_in,
                              void* d_out, int out_size, void* d_ws, size_t ws_size,
                              hipStream_t stream) {
    const int*   atom_types = (const int*)d_in[0];
    const float* frac       = (const float*)d_in[1];
    const float* lat        = (const float*)d_in[2];
    const float* node_emb   = (const float*)d_in[5];
    const float* ew1        = (const float*)d_in[6];
    const float* eb1        = (const float*)d_in[7];
    const float* ew2        = (const float*)d_in[8];
    const float* eb2        = (const float*)d_in[9];
    const float* nw1        = (const float*)d_in[10];
    const float* nb1        = (const float*)d_in[11];
    const float* nw2        = (const float*)d_in[12];
    const float* nb2        = (const float*)d_in[13];
    const float* ow         = (const float*)d_in[14];
    float* out = (float*)d_out;

    char* ws = (char*)d_ws;
    uint4* disP = (uint4*)ws; ws += (size_t)NBLK*1024*16;          // 16 MB
    uint4* wp   = (uint4*)ws; ws += (size_t)LL*FR_PER_L*64*16;     // 832 KB
    float* hA   = (float*)ws; ws += (size_t)NNODE*HH*4;            // 2 MB
    float* hB   = (float*)ws; ws += (size_t)NNODE*HH*4;            // 2 MB
    float* Cc   = (float*)ws; ws += (size_t)LL*BB*HH*4;            // 256 KB

    k_prep<<<2152, 256, 0, stream>>>(atom_types, frac, lat, node_emb,
                                     ew1, eb1, ew2, nw1, nw2,
                                     disP, wp, hA, Cc);

    float* hin = hA; float* hout = hB;
    for (int l = 0; l < LL; ++l) {
        k_layer<<<NBLK, 256, 0, stream>>>(hin, hout, disP, wp + (size_t)l*FR_PER_L*64,
                                          Cc + (size_t)l*BB*HH, eb2 + (size_t)l*HH,
                                          nb1 + (size_t)l*HH, nb2 + (size_t)l*HH);
        float* tmp = hin; hin = hout; hout = tmp;
    }
    k_pool<<<BB, HH, 0, stream>>>(hin, ow, out);
}

// Round 7
// 222.228 us; speedup vs baseline: 3.4875x; 1.0943x over previous
//
#include <hip/hip_runtime.h>
#include <hip/hip_bf16.h>
#include <cstdint>

#define HH 128
#define LL 4
#define BB 128
#define NNODE 4096
#define EIN 325
#define NBLK 1024            // block = (b, q4): 4 src x 32 dst = 128 edges

// packed-weight fragment offsets (per layer, 1KB frags)
#define OFF_W1  0            // [W1a(4ks);W1b(4ks);W1d(2ks)] : 10 ks x 8 nf = 80
#define OFF_W2  80           // 4 ks x 8 nf = 32
#define OFF_NW1 112          // 8 ks x 8 nf = 64
#define OFF_NW2 176          // 4 ks x 8 nf = 32
#define FR_PER_L 208

typedef __attribute__((ext_vector_type(8))) short short8;
typedef __attribute__((ext_vector_type(4))) float float4v;

#define MFMA __builtin_amdgcn_mfma_f32_16x16x32_bf16

__device__ __forceinline__ float silu_f(float x) {
    return x / (1.0f + __expf(-x));
}

__device__ __forceinline__ uint16_t f2bf(float x) {
    uint32_t u = __builtin_bit_cast(uint32_t, x);
    u += 0x7FFFu + ((u >> 16) & 1u);   // RNE
    return (uint16_t)(u >> 16);
}

__device__ __forceinline__ short8 ldw(const uint4* wpl, int fidx, int lane) {
    return *reinterpret_cast<const short8*>(&wpl[(size_t)fidx*64 + lane]);
}

// ---------- fused prep kernel: roles by blockIdx ----------
// [0,1024): dis pack   [1024,1128): weight pack   [1128,1640): Cc   [1640,2152): h0
__global__ __launch_bounds__(256) void k_prep(
    const int* __restrict__ at, const float* __restrict__ frac,
    const float* __restrict__ lat, const float* __restrict__ emb,
    const float* __restrict__ ew1, const float* __restrict__ eb1,
    const float* __restrict__ ew2, const float* __restrict__ nw1,
    const float* __restrict__ nw2,
    uint4* __restrict__ disP, uint4* __restrict__ wp,
    float* __restrict__ h0, float* __restrict__ Cc)
{
    __shared__ uint16_t sm[8192];    // 16KB; cc role aliases first bytes as float[9]
    int gid = blockIdx.x, t = threadIdx.x;

    if (gid < 1024) {
        // ---- dis: 128 edges -> 16 MFMA A-frags (2 ks x 8 mtiles) ----
        #pragma unroll
        for (int z = 0; z < 4; ++z) ((uint4*)sm)[t + 256*z] = uint4{0,0,0,0};
        __syncthreads();
        int b = gid >> 3, q4 = gid & 7;
        int e2 = t >> 1, half = t & 1;
        int i = q4*4 + (e2 >> 5), j = e2 & 31;
        float dx[3];
        #pragma unroll
        for (int d = 0; d < 3; ++d)
            dx[d] = frac[(b*32 + j)*3 + d] - frac[(b*32 + i)*3 + d];
        int T = e2 >> 4, rr = e2 & 15;
        #pragma unroll
        for (int kk = 0; kk < 30; ++kk) {
            int d = kk / 10, f = kk % 10;
            float ang = 6.28318530717958647692f * (float)f * dx[d];
            float v = half ? __cosf(ang) : __sinf(ang);
            int k = kk + 30*half;
            int ks = k >> 5, g = (k >> 3) & 3, ii = k & 7;
            sm[((ks*8 + T)*64 + g*16 + rr)*8 + ii] = f2bf(v);
        }
        __syncthreads();
        uint4* dst = disP + (size_t)gid * 1024;
        const uint4* smv = (const uint4*)sm;
        #pragma unroll
        for (int z = 0; z < 4; ++z) dst[t + 256*z] = smv[t + 256*z];
    } else if (gid < 1128) {
        // ---- weight pack ----
        int jidx = gid - 1024;
        int lay = jidx / 26, jj = jidx % 26;
        int wv = t >> 6, lane = t & 63, g = lane >> 4, col = lane & 15;
        int ks, base, type;
        if (jj < 10)      { ks = jj;      base = OFF_W1;  type = 0; }
        else if (jj < 14) { ks = jj - 10; base = OFF_W2;  type = 1; }
        else if (jj < 22) { ks = jj - 14; base = OFF_NW1; type = 2; }
        else              { ks = jj - 22; base = OFF_NW2; type = 3; }
        for (int nn = 0; nn < 2; ++nn) {
            int nf = 2*wv + nn;
            int n = nf*16 + col;
            uint16_t vals[8];
            #pragma unroll
            for (int ii = 0; ii < 8; ++ii) {
                int gk = 32*ks + 8*g + ii;
                float v = 0.f;
                if (type == 0) {
                    if (gk < 256)       v = ew1[((size_t)lay*EIN + gk)*HH + n];
                    else if (gk < 316)  v = ew1[((size_t)lay*EIN + gk + 9)*HH + n];
                } else if (type == 1)   v = ew2[((size_t)lay*HH + gk)*HH + n];
                else if (type == 2)     v = nw1[((size_t)lay*2*HH + gk)*HH + n];
                else                    v = nw2[((size_t)lay*HH + gk)*HH + n];
                vals[ii] = f2bf(v);
            }
            wp[((size_t)lay*FR_PER_L + base + ks*8 + nf)*64 + lane] = *(const uint4*)vals;
        }
    } else if (gid < 1640) {
        // ---- Cc = eb1 + lat_ip @ W1c ----
        float* lip = (float*)sm;
        int blk = gid - 1128;
        int lay = blk >> 7, b = blk & 127;
        if (t < 9) {
            int i = t / 3, k2 = t % 3;
            const float* lb = lat + b*9;
            lip[t] = lb[i*3]*lb[k2*3] + lb[i*3+1]*lb[k2*3+1] + lb[i*3+2]*lb[k2*3+2];
        }
        __syncthreads();
        if (t < 128) {
            float acc = eb1[lay*HH + t];
            #pragma unroll
            for (int k = 0; k < 9; ++k)
                acc += lip[k] * ew1[((size_t)lay*EIN + 2*HH + k)*HH + t];
            Cc[(size_t)blk*HH + t] = acc;
        }
    } else {
        // ---- h0 gather (vectorized) ----
        int idx = (gid - 1640)*256 + t;    // < 131072
        int n = idx >> 5, cq = idx & 31;
        float4v v = *(const float4v*)&emb[((size_t)(at[n]-1))*HH + cq*4];
        *(float4v*)&h0[(size_t)n*HH + cq*4] = v;
    }
}

// ---------- fused layer kernel ----------
// block = (b,q4): src nodes b*32+q4*4+{0..3}, all 32 dst. M=128 edges. 4 waves (2x2).
// m1 = Cc + A'[src] (acc init) + dis@W1d (MFMA) + Bv[dst] (fp32 LDS adds).
__global__ __launch_bounds__(256, 3) void k_layer(
    const float* __restrict__ h_in, float* __restrict__ h_out,
    const uint4* __restrict__ disP, const uint4* __restrict__ wpl,
    const float* __restrict__ Cc_l, const float* __restrict__ b2,
    const float* __restrict__ nb1, const float* __restrict__ nb2)
{
    __shared__ uint4 smem4[2688];                // 43008 B
    char* smem = (char*)smem4;
    char* hHi = smem;                            // [32] rows x 256B bf16, XOR-swizzled
    float* Af = (float*)(smem + 8192);           // [4][132] f32 A' = h_src @ W1a
    float* Bf = (float*)(smem + 10304);          // [32][132] f32 Bv = h @ W1b
    char* sS  = smem + 8192;                     // overlays Af/Bf after GEMM1: [128]x256B swizzled
    uint16_t* aggB = (uint16_t*)(smem + 40960);  // [4][128] bf16
    uint16_t* u1B  = (uint16_t*)(smem + 41984);  // [4][128] bf16

    int bid = blockIdx.x;
    int b = bid >> 3, q4 = bid & 7;
    int t = threadIdx.x;
    int w = t >> 6, l = t & 63;
    int wm = w >> 1, wn = w & 1;
    int g = l >> 4, rr = l & 15;

    // prefetch dis A-frags (global, long latency -> cover under P0/P1)
    short8 dfr[2][4];
    #pragma unroll
    for (int ks = 0; ks < 2; ++ks)
        #pragma unroll
        for (int mf = 0; mf < 4; ++mf)
            dfr[ks][mf] = *(const short8*)&disP[((size_t)(bid*2 + ks)*8 + 4*wm + mf)*64 + l];

    // ---- P0: stage h tile (32 rows) bf16, swizzled ----
    {
        int row = t >> 3, czb = (t & 7) * 16;
        const float* hp = h_in + (size_t)(b*32 + row)*HH + czb;
        uint16_t ph[16];
        #pragma unroll
        for (int z = 0; z < 16; z += 4) {
            float4v v = *(const float4v*)(hp + z);
            #pragma unroll
            for (int y = 0; y < 4; ++y) ph[z+y] = f2bf(v[y]);
        }
        int sw = (row & 7) << 4;
        int base = row * 256;
        *(uint4*)(hHi + base + ((2*czb) ^ sw))      = *(const uint4*)&ph[0];
        *(uint4*)(hHi + base + ((2*czb + 16) ^ sw)) = *(const uint4*)&ph[8];
    }
    __syncthreads();

    // ---- P1: A' = h_src@W1a (mt0, rows replicated), Bv = h@W1b (mt1,2); wave owns 2 nf cols ----
    {
        float4v pacc[3][2];
        #pragma unroll
        for (int mt = 0; mt < 3; ++mt)
            #pragma unroll
            for (int nfl = 0; nfl < 2; ++nfl) pacc[mt][nfl] = (float4v){0.f,0.f,0.f,0.f};
        #pragma unroll
        for (int ks = 0; ks < 4; ++ks) {
            short8 wa[2], wb[2];
            #pragma unroll
            for (int nfl = 0; nfl < 2; ++nfl) {
                wa[nfl] = ldw(wpl, OFF_W1      + ks*8 + 2*w + nfl, l);
                wb[nfl] = ldw(wpl, OFF_W1 + 32 + ks*8 + 2*w + nfl, l);
            }
            #pragma unroll
            for (int mt = 0; mt < 3; ++mt) {
                int R = (mt == 0) ? (q4*4 + (rr & 3)) : ((mt - 1)*16 + rr);
                short8 a = *(const short8*)(hHi + R*256 + ((64*ks + 16*g) ^ ((R & 7) << 4)));
                #pragma unroll
                for (int nfl = 0; nfl < 2; ++nfl)
                    pacc[mt][nfl] = MFMA(a, (mt == 0) ? wa[nfl] : wb[nfl], pacc[mt][nfl], 0, 0, 0);
            }
        }
        // write Af (rows 0..3, g==0 lanes) and Bf (rows 0..31), fp32, stride 132
        #pragma unroll
        for (int nfl = 0; nfl < 2; ++nfl) {
            int n = 32*w + 16*nfl + rr;
            if (g == 0) {
                #pragma unroll
                for (int r = 0; r < 4; ++r) Af[r*132 + n] = pacc[0][nfl][r];
            }
            #pragma unroll
            for (int r = 0; r < 4; ++r) Bf[(4*g + r)*132 + n]      = pacc[1][nfl][r];
            #pragma unroll
            for (int r = 0; r < 4; ++r) Bf[(16 + 4*g + r)*132 + n] = pacc[2][nfl][r];
        }
    }
    __syncthreads();

    float ccv[4], b2v[4];
    #pragma unroll
    for (int nf = 0; nf < 4; ++nf) {
        ccv[nf] = Cc_l[b*HH + 64*wn + 16*nf + rr];
        b2v[nf] = b2[64*wn + 16*nf + rr];
    }

    // ---- GEMM1: acc = (Cc + A'[src]) + dis@W1d, then += Bv[dst] ----
    float4v acc[4][4];
    #pragma unroll
    for (int mf = 0; mf < 4; ++mf) {
        int srcr = 2*wm + (mf >> 1);     // = T>>1, T = 4*wm+mf
        #pragma unroll
        for (int nf = 0; nf < 4; ++nf) {
            float iv = ccv[nf] + Af[srcr*132 + 64*wn + 16*nf + rr];
            acc[mf][nf] = (float4v){iv, iv, iv, iv};
        }
    }
    #pragma unroll
    for (int ks = 0; ks < 2; ++ks) {
        short8 wf[4];
        #pragma unroll
        for (int nf = 0; nf < 4; ++nf)
            wf[nf] = ldw(wpl, OFF_W1 + 64 + ks*8 + 4*wn + nf, l);
        #pragma unroll
        for (int mf = 0; mf < 4; ++mf)
            #pragma unroll
            for (int nf = 0; nf < 4; ++nf)
                acc[mf][nf] = MFMA(dfr[ks][mf], wf[nf], acc[mf][nf], 0, 0, 0);
    }
    {
        float bval[2][4][4];             // [T&1][r][nf]
        #pragma unroll
        for (int par = 0; par < 2; ++par)
            #pragma unroll
            for (int r = 0; r < 4; ++r)
                #pragma unroll
                for (int nf = 0; nf < 4; ++nf)
                    bval[par][r][nf] = Bf[(16*par + 4*g + r)*132 + 64*wn + 16*nf + rr];
        #pragma unroll
        for (int mf = 0; mf < 4; ++mf)
            #pragma unroll
            for (int nf = 0; nf < 4; ++nf)
                #pragma unroll
                for (int r = 0; r < 4; ++r)
                    acc[mf][nf][r] += bval[mf & 1][r][nf];
    }
    __syncthreads();   // all Af/Bf reads done before sS overlay writes

    // ---- silu -> sS (swizzled bf16) ----
    #pragma unroll
    for (int mf = 0; mf < 4; ++mf) {
        int T = 4*wm + mf;
        #pragma unroll
        for (int nf = 0; nf < 4; ++nf) {
            int n = 64*wn + 16*nf + rr;
            #pragma unroll
            for (int r = 0; r < 4; ++r) {
                int m = 16*T + 4*g + r;
                *(uint16_t*)(sS + m*256 + ((2*n) ^ ((m & 7) << 4))) = f2bf(silu_f(acc[mf][nf][r]));
            }
        }
    }
    __syncthreads();

    // ---- GEMM2: s(128x128) @ W2 ----
    #pragma unroll
    for (int mf = 0; mf < 4; ++mf)
        #pragma unroll
        for (int nf = 0; nf < 4; ++nf)
            acc[mf][nf] = (float4v){0.f, 0.f, 0.f, 0.f};
    #pragma unroll
    for (int ks = 0; ks < 4; ++ks) {
        short8 wf[4];
        #pragma unroll
        for (int nf = 0; nf < 4; ++nf)
            wf[nf] = ldw(wpl, OFF_W2 + ks*8 + 4*wn + nf, l);
        #pragma unroll
        for (int mf = 0; mf < 4; ++mf) {
            int m = 16*(4*wm + mf) + rr;
            short8 a = *(const short8*)(sS + m*256 + ((64*ks + 16*g) ^ ((m & 7) << 4)));
            #pragma unroll
            for (int nf = 0; nf < 4; ++nf)
                acc[mf][nf] = MFMA(a, wf[nf], acc[mf][nf], 0, 0, 0);
        }
    }

    // ---- +b2, silu, mean over 32 j -> aggB bf16 ----
    #pragma unroll
    for (int u = 0; u < 2; ++u) {            // i_loc = 2*wm + u
        #pragma unroll
        for (int nf = 0; nf < 4; ++nf) {
            float v = 0.f;
            #pragma unroll
            for (int mm = 0; mm < 2; ++mm)
                #pragma unroll
                for (int r = 0; r < 4; ++r)
                    v += silu_f(acc[2*u + mm][nf][r] + b2v[nf]);
            v += __shfl_xor(v, 16);
            v += __shfl_xor(v, 32);
            if (g == 0)
                aggB[(2*wm + u)*128 + 64*wn + 16*nf + rr] = f2bf(v * (1.0f/32.0f));
        }
    }
    __syncthreads();

    // ---- node MLP1: [h | agg] @ NW1 ----
    float4v uacc[2];
    #pragma unroll
    for (int nfl = 0; nfl < 2; ++nfl) uacc[nfl] = (float4v){0.f, 0.f, 0.f, 0.f};
    #pragma unroll
    for (int ks = 0; ks < 8; ++ks) {
        short8 a;
        if (ks < 4) {
            int R = q4*4 + (rr & 3);
            a = *(const short8*)(hHi + R*256 + ((64*ks + 16*g) ^ ((R & 7) << 4)));
        } else {
            a = *(const short8*)&aggB[(rr & 3)*128 + 32*(ks - 4) + 8*g];
        }
        #pragma unroll
        for (int nfl = 0; nfl < 2; ++nfl)
            uacc[nfl] = MFMA(a, ldw(wpl, OFF_NW1 + ks*8 + 2*w + nfl, l), uacc[nfl], 0, 0, 0);
    }
    if (g == 0) {
        #pragma unroll
        for (int nfl = 0; nfl < 2; ++nfl)
            #pragma unroll
            for (int r = 0; r < 4; ++r) {
                int col = (2*w + nfl)*16 + rr;
                u1B[r*128 + col] = f2bf(silu_f(uacc[nfl][r] + nb1[col]));
            }
    }
    __syncthreads();

    // ---- node MLP2 + residual ----
    float4v vacc[2];
    #pragma unroll
    for (int nfl = 0; nfl < 2; ++nfl) vacc[nfl] = (float4v){0.f, 0.f, 0.f, 0.f};
    #pragma unroll
    for (int ks = 0; ks < 4; ++ks) {
        short8 a = *(const short8*)&u1B[(rr & 3)*128 + 32*ks + 8*g];
        #pragma unroll
        for (int nfl = 0; nfl < 2; ++nfl)
            vacc[nfl] = MFMA(a, ldw(wpl, OFF_NW2 + ks*8 + 2*w + nfl, l), vacc[nfl], 0, 0, 0);
    }
    if (g == 0) {
        #pragma unroll
        for (int nfl = 0; nfl < 2; ++nfl)
            #pragma unroll
            for (int r = 0; r < 4; ++r) {
                int col = (2*w + nfl)*16 + rr;
                size_t node = (size_t)(b*32 + q4*4 + r);
                h_out[node*HH + col] = h_in[node*HH + col] + silu_f(vacc[nfl][r] + nb2[col]);
            }
    }
}

// graph mean-pool + out projection
__global__ __launch_bounds__(128) void k_pool(const float* __restrict__ h, const float* __restrict__ ow,
                       float* __restrict__ out) {
    __shared__ float sm_g[HH];
    int b = blockIdx.x, c = threadIdx.x;
    float s = 0.f;
    for (int n = 0; n < 32; ++n) s += h[(size_t)(b*32 + n)*HH + c];
    sm_g[c] = s * (1.0f/32.0f);
    __syncthreads();
    float acc = 0.f;
    for (int k = 0; k < HH; ++k) acc += sm_g[k] * ow[k*HH + c];
    out[(size_t)b*HH + c] = acc;
}

extern "C" void kernel_launch(void* const* d_in, const int* in_sizes, int n_in,
                              void* d_out, int out_size, void* d_ws, size_t ws_size,
                              hipStream_t stream) {
    const int*   atom_types = (const int*)d_in[0];
    const float* frac       = (const float*)d_in[1];
    const float* lat        = (const float*)d_in[2];
    const float* node_emb   = (const float*)d_in[5];
    const float* ew1        = (const float*)d_in[6];
    const float* eb1        = (const float*)d_in[7];
    const float* ew2        = (const float*)d_in[8];
    const float* eb2        = (const float*)d_in[9];
    const float* nw1        = (const float*)d_in[10];
    const float* nb1        = (const float*)d_in[11];
    const float* nw2        = (const float*)d_in[12];
    const float* nb2        = (const float*)d_in[13];
    const float* ow         = (const float*)d_in[14];
    float* out = (float*)d_out;

    char* ws = (char*)d_ws;
    uint4* disP = (uint4*)ws; ws += (size_t)NBLK*1024*16;          // 16 MB
    uint4* wp   = (uint4*)ws; ws += (size_t)LL*FR_PER_L*64*16;     // 832 KB
    float* hA   = (float*)ws; ws += (size_t)NNODE*HH*4;            // 2 MB
    float* hB   = (float*)ws; ws += (size_t)NNODE*HH*4;            // 2 MB
    float* Cc   = (float*)ws; ws += (size_t)LL*BB*HH*4;            // 256 KB

    k_prep<<<2152, 256, 0, stream>>>(atom_types, frac, lat, node_emb,
                                     ew1, eb1, ew2, nw1, nw2,
                                     disP, wp, hA, Cc);

    float* hin = hA; float* hout = hB;
    for (int l = 0; l < LL; ++l) {
        k_layer<<<NBLK, 256, 0, stream>>>(hin, hout, disP, wp + (size_t)l*FR_PER_L*64,
                                          Cc + (size_t)l*BB*HH, eb2 + (size_t)l*HH,
                                          nb1 + (size_t)l*HH, nb2 + (size_t)l*HH);
        float* tmp = hin; hin = hout; hout = tmp;
    }
    k_pool<<<BB, HH, 0, stream>>>(hin, ow, out);
}